// Round 12
// baseline (336.644 us; speedup 1.0000x reference)
//
#include <hip/hip_runtime.h>
#include <hip/hip_bf16.h>
#include <math.h>

typedef __hip_bfloat16 bf16;
typedef short bf16x8 __attribute__((ext_vector_type(8)));
typedef float floatx4 __attribute__((ext_vector_type(4)));

#define NTOK 841          // 29*29 patches
#define BATCH 8
#define DIM 256
#define HEADS 8
#define DH 32
#define IMG 457
#define HPAD 464
#define ROWS (BATCH * NTOK)   // 6728
#define LDA 40                // padded LDS row stride (bf16 elems) -> 80B

// weight segment offsets (elements) in the packed bf16 weight buffer
#define W_SPT   0
#define W_QKV   327680
#define W_OUT   917504
#define W_FF1   1114112
#define W_FF2   1900544
#define W_PIX   2686976
#define W_TOTAL 2752512

// ---------------------------------------------------------------------------
// Fast gelu (exact-erf variant): Abramowitz-Stegun 7.1.26, |err| <= 1.5e-7
// absolute on erf — far below bf16 output quantization. (R20, neutral-proven)
// ---------------------------------------------------------------------------
__device__ __forceinline__ float fast_gelu(float v) {
    float x = v * 0.70710678118654752f;
    float ax = fabsf(x);
    float t = __builtin_amdgcn_rcpf(1.0f + 0.3275911f * ax);
    float p = t * (0.254829592f +
              t * (-0.284496736f +
              t * (1.421413741f +
              t * (-1.453152027f +
              t * 1.061405429f))));
    float e = __expf(-x * x);
    float erfa = 1.0f - p * e;            // erf(|x|)
    float erfx = copysignf(erfa, x);
    return 0.5f * v * (1.0f + erfx);
}

// ---------------------------------------------------------------------------
// Convert all weight tensors fp32 -> bf16 into one packed buffer.
// ---------------------------------------------------------------------------
__global__ __launch_bounds__(256) void wconv_kernel(
    const float* __restrict__ s_spt, const float* __restrict__ s_qkv,
    const float* __restrict__ s_out, const float* __restrict__ s_ff1,
    const float* __restrict__ s_ff2, const float* __restrict__ s_pix,
    bf16* __restrict__ dst) {
    int idx = (blockIdx.x * 256 + threadIdx.x) * 4;
    const float* src; int off;
    if      (idx < W_QKV) { src = s_spt; off = W_SPT; }
    else if (idx < W_OUT) { src = s_qkv; off = W_QKV; }
    else if (idx < W_FF1) { src = s_out; off = W_OUT; }
    else if (idx < W_FF2) { src = s_ff1; off = W_FF1; }
    else if (idx < W_PIX) { src = s_ff2; off = W_FF2; }
    else                  { src = s_pix; off = W_PIX; }
    float4 v = *(const float4*)(src + (idx - off));
    union { ushort4 u; bf16 h[4]; } pk;
    pk.h[0] = __float2bfloat16(v.x);
    pk.h[1] = __float2bfloat16(v.y);
    pk.h[2] = __float2bfloat16(v.z);
    pk.h[3] = __float2bfloat16(v.w);
    *(ushort4*)(dst + idx) = pk.u;
}

// ---------------------------------------------------------------------------
// Tokenize gather -> bf16 tok[ROWS][1280], k=(c,py,px).  (R6 proven)
// ---------------------------------------------------------------------------
__global__ __launch_bounds__(256) void tokenize_kernel(const float* __restrict__ x,
                                                       bf16* __restrict__ tok) {
    int idx = blockIdx.x * 256 + threadIdx.x;
    int gm = idx / 320;
    int k4 = (idx - gm * 320) * 4;
    int b = gm / NTOK;
    int n = gm - b * NTOK;
    int hp = n / 29, wp = n - (n / 29) * 29;
    int c = k4 >> 8;
    int py = (k4 >> 4) & 15;
    int px0 = k4 & 15;
    const int dxs[5] = {0, -8, 8, -8, 8};
    const int dys[5] = {0, -8, -8, 8, 8};
    int r = hp * 16 + py - dys[c];
    r += (r < 0) ? HPAD : 0; r -= (r >= HPAD) ? HPAD : 0;
    bool rok = (r < IMG);
    union { ushort4 u; bf16 h[4]; } pk;
#pragma unroll
    for (int i = 0; i < 4; i++) {
        int s = wp * 16 + px0 + i - dxs[c];
        s += (s < 0) ? HPAD : 0; s -= (s >= HPAD) ? HPAD : 0;
        float v = 0.0f;
        if (rok && s < IMG) v = x[((size_t)b * IMG + r) * IMG + s];
        pk.h[i] = __float2bfloat16(v);
    }
    *(ushort4*)(tok + (size_t)gm * 1280 + k4) = pk.u;
}

// ---------------------------------------------------------------------------
// Double-buffered MFMA GEMM: C = A@W^T, BK=32, 4 waves (2x2).
// Proven shapes (R14/R16): 64x64 for wide-N GEMMs.
// FAILED structural edits (fence): R18 64x128 (+78us, VGPR cliff); R19
// A-direct-global (+49us); R23 BK=64 (+182us, latency-bound staging
// diagnosed: MfmaUtil 2.8%, Occ 28%); R26 depth-2 prefetch (neutral);
// R27 split-K atomics (+223us: cross-XCD atomic RMW ~uncached).
// R29 (occupancy axis, no atomics): N=256 family moves 32x64 -> 32x32.
// Grid (4,211)=844 -> (8,211)=1688 blocks = 6.6 blocks/CU = 26 waves/CU
// (vs 13). K-loop/barriers/wave-layout untouched; LDS 10.2KB; A re-reads
// double but all A buffers are L3-resident. Tests the occupancy hypothesis
// cleanly: R27 failed on atomics, not on the occupancy mechanism.
// ---------------------------------------------------------------------------
template <int BM, int BN>
__global__ __launch_bounds__(256) void gemm_db_kernel(
    const bf16* __restrict__ A, const bf16* __restrict__ W,
    const float* __restrict__ bias, const float* __restrict__ resid,
    const float* __restrict__ posemb, float* __restrict__ Cf,
    bf16* __restrict__ Cb, int M, int N, int K, int act) {
    constexpr int WM = BM / 2, WN = BN / 2;
    constexpr int TI = WM / 16, TJ = WN / 16;
    constexpr int ACHUNKS = BM * 4;            // 16B chunks per A k-tile
    constexpr int BCHUNKS = BN * 4;
    static_assert(ACHUNKS <= 256 && BCHUNKS <= 256, "one chunk per thread");
    __shared__ bf16 As[2][BM * LDA];
    __shared__ bf16 Bs[2][BN * LDA];
    const int tid = threadIdx.x;
    const int m0 = blockIdx.y * BM, n0 = blockIdx.x * BN;
    const int w = tid >> 6, lane = tid & 63;
    const int wm = (w >> 1) * WM, wn = (w & 1) * WN;
    const int li = lane & 15, quad = lane >> 4;

    floatx4 acc[TI][TJ] = {};
    float4 a0, b0, a1, b1;               // ping-pong staging sets (R26)

    const int arow = tid >> 2, ako = (tid & 3) << 3;   // staging coords
    const bool a_on = tid < ACHUNKS;
    const bool b_on = tid < BCHUNKS;

    auto load_a = [&](float4& ar, int k0) {
        if (a_on) {
            int gm = m0 + arow;
            ar = make_float4(0.f, 0.f, 0.f, 0.f);
            if (gm < M) ar = *(const float4*)(A + (size_t)gm * K + k0 + ako);
        }
    };
    auto load_b = [&](float4& br, int k0) {
        if (b_on) br = *(const float4*)(W + (size_t)(n0 + arow) * K + k0 + ako);
    };
    auto store_ab = [&](int buf, const float4& ar, const float4& br) {
        if (a_on) *(float4*)&As[buf][arow * LDA + ako] = ar;
        if (b_on) *(float4*)&Bs[buf][arow * LDA + ako] = br;
    };
    auto compute = [&](int buf) {
        bf16x8 af[TI], bfr[TJ];
#pragma unroll
        for (int t = 0; t < TI; t++)
            af[t] = *(const bf16x8*)&As[buf][(wm + t * 16 + li) * LDA + quad * 8];
#pragma unroll
        for (int t = 0; t < TJ; t++)
            bfr[t] = *(const bf16x8*)&Bs[buf][(wn + t * 16 + li) * LDA + quad * 8];
#pragma unroll
        for (int ti = 0; ti < TI; ti++)
#pragma unroll
            for (int tj = 0; tj < TJ; tj++)
                acc[ti][tj] = __builtin_amdgcn_mfma_f32_16x16x32_bf16(
                    af[ti], bfr[tj], acc[ti][tj], 0, 0, 0);
    };

    const int ktiles = K >> 5;           // 8 / 32 / 40 — always even
    // prologue: tile0 -> LDS0; set0 <- tile1; set1 <- tile2
    load_a(a0, 0); load_b(b0, 0);
    store_ab(0, a0, b0);
    if (ktiles > 1) { load_a(a0, 32); load_b(b0, 32); }
    if (ktiles > 2) { load_a(a1, 64); load_b(b1, 64); }
    __syncthreads();

    for (int kt = 0; kt < ktiles; kt += 2) {
        compute(0);                                   // tile kt
        if (kt + 1 < ktiles) store_ab(1, a0, b0);     // set0 holds tile kt+1
        if (kt + 3 < ktiles) { load_a(a0, (kt + 3) << 5); load_b(b0, (kt + 3) << 5); }
        __syncthreads();
        compute(1);                                   // tile kt+1
        if (kt + 2 < ktiles) store_ab(0, a1, b1);     // set1 holds tile kt+2
        if (kt + 4 < ktiles) { load_a(a1, (kt + 4) << 5); load_b(b1, (kt + 4) << 5); }
        __syncthreads();
    }

#pragma unroll
    for (int ti = 0; ti < TI; ti++) {
#pragma unroll
        for (int r = 0; r < 4; r++) {
            int gm = m0 + wm + ti * 16 + quad * 4 + r;
            if (gm >= M) continue;
#pragma unroll
            for (int tj = 0; tj < TJ; tj++) {
                int gn = n0 + wn + tj * 16 + li;
                float v = acc[ti][tj][r];
                if (bias) v += bias[gn];
                if (act == 1) v = fast_gelu(v);
                if (posemb) v += posemb[(size_t)(gm % NTOK) * N + gn];
                if (resid) v += resid[(size_t)gm * N + gn];
                if (Cf) Cf[(size_t)gm * N + gn] = v;
                if (Cb) Cb[(size_t)gm * N + gn] = __float2bfloat16(v);
            }
        }
    }
}

// ---------------------------------------------------------------------------
// LayerNorm over last dim (256). One wave per row, 4 rows per block.
// ---------------------------------------------------------------------------
__global__ __launch_bounds__(256) void ln_kernel(const float* __restrict__ in,
                                                 const float* __restrict__ w,
                                                 const float* __restrict__ b,
                                                 bf16* __restrict__ out) {
    const int lane = threadIdx.x & 63;
    const int wv = threadIdx.x >> 6;
    const size_t row = (size_t)blockIdx.x * 4 + wv;
    const int c = lane * 4;
    float4 x = *(const float4*)&in[row * DIM + c];
    float s = x.x + x.y + x.z + x.w;
    float s2 = x.x * x.x + x.y * x.y + x.z * x.z + x.w * x.w;
#pragma unroll
    for (int off = 1; off < 64; off <<= 1) {
        s += __shfl_xor(s, off);
        s2 += __shfl_xor(s2, off);
    }
    float mean = s * (1.0f / DIM);
    float var = s2 * (1.0f / DIM) - mean * mean;
    float rstd = rsqrtf(var + 1e-5f);
    float4 w4 = *(const float4*)&w[c];
    float4 b4 = *(const float4*)&b[c];
    union { ushort4 u; bf16 h[4]; } pk;
    pk.h[0] = __float2bfloat16((x.x - mean) * rstd * w4.x + b4.x);
    pk.h[1] = __float2bfloat16((x.y - mean) * rstd * w4.y + b4.y);
    pk.h[2] = __float2bfloat16((x.z - mean) * rstd * w4.z + b4.z);
    pk.h[3] = __float2bfloat16((x.w - mean) * rstd * w4.w + b4.w);
    *(ushort4*)&out[row * DIM + c] = pk.u;
}

// ---------------------------------------------------------------------------
// MFMA flash attention, 256 threads, 1-barrier j-loop (R10 proven structure).
// R21 (-10.5us): row-sum l via PV MFMA with all-ones B. R22 (-14.8us):
// fixed-shift softmax (M=8). R24 (-2.4us): Vt j-column rotation (bank fix).
// R25 (neutral, kept): Q-frag hoist + mask-free interior tiles.
// R28 (neutral, kept): swapped QK^T operands + packed 8B Ps writes.
// Attn plateau: remaining cost is the barrier/staging skeleton itself.
// ---------------------------------------------------------------------------
#define LQ 40    // Qs/Ks row stride (bf16)
#define LP 72    // Ps/Vt row stride (bf16)
__global__ __launch_bounds__(256) void attn_mfma_kernel(
    const bf16* __restrict__ qkv, const float* __restrict__ scale,
    bf16* __restrict__ out) {
    __shared__ bf16 Qs[64 * LQ];        // [i][d]
    __shared__ bf16 Ks[2][64 * LQ];     // [j][d]
    __shared__ bf16 Vt[2][32 * LP];     // [d][j-rotated]
    __shared__ bf16 Ps[64 * LP];        // [i][j], wave-private row bands

    const int tid = threadIdx.x;
    const int bh = blockIdx.x;
    const int b = bh >> 3, h = bh & 7;
    const int it = (int)gridDim.y - 1 - (int)blockIdx.y;   // longest first
    const int i0 = it * 64;
    const float sc = scale[h];
    const float sc2 = sc * 1.44269504f;          // fold scale + log2(e)
    const float mshift = -8.0f * 1.44269504f;    // fixed shift M=8 (log2 units)
    const bf16* base = qkv + (size_t)b * NTOK * 768 + h * DH;

    const int w = tid >> 6, lane = tid & 63;
    const int li = lane & 15, quad = lane >> 4;
    const int srow = tid >> 2, sd0 = (tid & 3) * 8;   // staging coords
    const int vcol = (srow + ((tid & 3) << 4)) & 63;  // R24 rotated j-column

    {
        int gi = i0 + srow;
        bf16x8 v = {};
        if (gi < NTOK) v = *(const bf16x8*)(base + (size_t)gi * 768 + sd0);
        *(bf16x8*)&Qs[srow * LQ + sd0] = v;
    }
    bf16x8 kreg = {}, vreg = {};
    {
        int gj = srow;
        if (gj < NTOK) {
            kreg = *(const bf16x8*)(base + (size_t)gj * 768 + 256 + sd0);
            vreg = *(const bf16x8*)(base + (size_t)gj * 768 + 512 + sd0);
        }
    }
    __syncthreads();   // Q staging visible -> aq can be hoisted (R25a)
    const bf16x8 aq = *(const bf16x8*)&Qs[(w * 16 + li) * LQ + quad * 8];

    // all-ones bf16 B-fragment for the row-sum MFMA (1.0bf16 = 0x3F80)
    const bf16x8 ones8 = {(short)0x3F80, (short)0x3F80, (short)0x3F80, (short)0x3F80,
                          (short)0x3F80, (short)0x3F80, (short)0x3F80, (short)0x3F80};

    floatx4 o[2] = {};
    floatx4 o2 = {};                     // running row sums (R21)
    const bool interior_ok = (i0 + 63 < NTOK);   // it <= 12
    const int gi2 = i0 + w * 16 + li;            // R28: lane's i (fixed)
    // Ps write base for this lane: row (w*16+li), col (quad*4), +16 per tj
    bf16* const psw = &Ps[(w * 16 + li) * LP + quad * 4];

    for (int jt = 0; jt <= it; jt++) {
        const int j0 = jt * 64;
        const int cur = jt & 1;
        *(bf16x8*)&Ks[cur][srow * LQ + sd0] = kreg;
#pragma unroll
        for (int u = 0; u < 8; u++) Vt[cur][(sd0 + u) * LP + vcol] = ((bf16*)&vreg)[u];
        if (jt < it) {
            int gj = j0 + 64 + srow;
            kreg = bf16x8{};
            vreg = bf16x8{};
            if (gj < NTOK) {
                kreg = *(const bf16x8*)(base + (size_t)gj * 768 + 256 + sd0);
                vreg = *(const bf16x8*)(base + (size_t)gj * 768 + 512 + sd0);
            }
        }
        __syncthreads();   // the only barrier per iteration

        // R28: swapped operands -> sacc[tj][r] = S[j0+tj*16+quad*4+r][gi2]
        floatx4 sacc[4];
#pragma unroll
        for (int tj = 0; tj < 4; tj++) {
            bf16x8 bk = *(const bf16x8*)&Ks[cur][(tj * 16 + li) * LQ + quad * 8];
            floatx4 z = {};
            sacc[tj] = __builtin_amdgcn_mfma_f32_16x16x32_bf16(bk, aq, z, 0, 0, 0);
        }

        if (jt < it && interior_ok) {
            // fast path: mask provably all-true for this wave (R25b)
#pragma unroll
            for (int tj = 0; tj < 4; tj++) {
                union { short4 u; bf16 h[4]; } pk;
#pragma unroll
                for (int r = 0; r < 4; r++)
                    pk.h[r] = __float2bfloat16(exp2f(fmaf(sacc[tj][r], sc2, mshift)));
                *(short4*)(psw + tj * 16) = pk.u;
            }
        } else {
#pragma unroll
            for (int tj = 0; tj < 4; tj++) {
                union { short4 u; bf16 h[4]; } pk;
#pragma unroll
                for (int r = 0; r < 4; r++) {
                    int j = j0 + tj * 16 + quad * 4 + r;
                    bool ok = (j < gi2) && (gi2 < NTOK);
                    float arg = ok ? fmaf(sacc[tj][r], sc2, mshift) : -1e30f;
                    pk.h[r] = __float2bfloat16(exp2f(arg));
                }
                *(short4*)(psw + tj * 16) = pk.u;
            }
        }
        // no barrier: Ps rows [16w,16w+16) written and read by wave w only.

#pragma unroll
        for (int kk = 0; kk < 64; kk += 32) {
            bf16x8 ap = *(const bf16x8*)&Ps[(w * 16 + li) * LP + kk + quad * 8];
#pragma unroll
            for (int td = 0; td < 2; td++) {
                const int kr = (2 * td + (li >> 3)) & 3;             // (d>>3)&3
                const int vc0 = (kk + quad * 8 + (kr << 4)) & 63;    // rotated base
                bf16x8 bv = *(const bf16x8*)&Vt[cur][(td * 16 + li) * LP + vc0];
                o[td] = __builtin_amdgcn_mfma_f32_16x16x32_bf16(ap, bv, o[td], 0, 0, 0);
            }
            // row-sum accumulation: every output column gets sum_j P (B = ones)
            o2 = __builtin_amdgcn_mfma_f32_16x16x32_bf16(ap, ones8, o2, 0, 0, 0);
        }
    }

#pragma unroll
    for (int r = 0; r < 4; r++) {
        int gi = i0 + w * 16 + quad * 4 + r;
        if (gi >= NTOK) continue;
        float l = o2[r];
        float iv = (gi > 0 && l > 0.0f) ? 1.0f / l : 0.0f;
        bf16* op = out + ((size_t)b * NTOK + gi) * DIM + h * DH;
        op[li]      = __float2bfloat16(o[0][r] * iv);
        op[16 + li] = __float2bfloat16(o[1][r] * iv);
    }
}

// ---------------------------------------------------------------------------
// Scatter pix [B, N, 256] fp32 -> out image [B,1,457,457] fp32 (crop)
// ---------------------------------------------------------------------------
__global__ __launch_bounds__(256) void scatter_kernel(const float* __restrict__ pix,
                                                      float* __restrict__ out) {
    const size_t total = (size_t)BATCH * IMG * IMG;
    size_t idx = (size_t)blockIdx.x * 256 + threadIdx.x;
    if (idx >= total) return;
    int b = (int)(idx / ((size_t)IMG * IMG));
    int rem = (int)(idx % ((size_t)IMG * IMG));
    int r = rem / IMG, col = rem % IMG;
    int hp = r >> 4, py = r & 15;
    int wp = col >> 4, px = col & 15;
    out[idx] = pix[((size_t)b * NTOK + hp * 29 + wp) * DIM + py * 16 + px];
}

// ---------------------------------------------------------------------------
extern "C" void kernel_launch(void* const* d_in, const int* in_sizes, int n_in,
                              void* d_out, int out_size, void* d_ws, size_t ws_size,
                              hipStream_t stream) {
    const float* x     = (const float*)d_in[0];
    const float* pos   = (const float*)d_in[1];
    const float* sptw  = (const float*)d_in[2];
    const float* sptb  = (const float*)d_in[3];
    const float* ln1w  = (const float*)d_in[4];
    const float* ln1b  = (const float*)d_in[5];
    const float* scale = (const float*)d_in[6];
    const float* wqkv  = (const float*)d_in[7];
    const float* wout  = (const float*)d_in[8];
    const float* bout  = (const float*)d_in[9];
    const float* ln2w  = (const float*)d_in[10];
    const float* ln2b  = (const float*)d_in[11];
    const float* ff1w  = (const float*)d_in[12];
    const float* ff1b  = (const float*)d_in[13];
    const float* ff2w  = (const float*)d_in[14];
    const float* ff2b  = (const float*)d_in[15];
    const float* pixw  = (const float*)d_in[16];
    const float* pixb  = (const float*)d_in[17];
    float* out = (float*)d_out;

    const size_t NT = (size_t)ROWS * DIM;
    char* ws = (char*)d_ws;
    float* t    = (float*)ws;                         ws += NT * 4;
    bf16*  tn_b = (bf16*)ws;                          ws += NT * 2;
    bf16*  t_b  = (bf16*)ws;                          ws += NT * 2;
    bf16*  ao_b = (bf16*)ws;                          ws += NT * 2;
    bf16*  wbf  = (bf16*)ws;                          ws += (size_t)W_TOTAL * 2;
    char*  big  = ws;                                  // time-shared region
    bf16*  tok   = (bf16*)big;
    bf16*  qkv_b = (bf16*)big;
    bf16*  ffh   = (bf16*)big;
    float* pixo  = (float*)big;

    wconv_kernel<<<W_TOTAL / 4 / 256, 256, 0, stream>>>(sptw, wqkv, wout, ff1w,
                                                        ff2w, pixw, wbf);
    tokenize_kernel<<<(ROWS * 320) / 256, 256, 0, stream>>>(x, tok);
    // SPT projection + bias + pos_emb -> t (fp32). 32x32 tiles (R29): 1688
    // blocks = 6.6/CU.
    gemm_db_kernel<32, 32><<<dim3(8, 211), 256, 0, stream>>>(
        tok, wbf + W_SPT, sptb, nullptr, pos, t, nullptr, ROWS, DIM, 1280, 0);

    for (int d = 0; d < 3; d++) {
        ln_kernel<<<ROWS / 4, 256, 0, stream>>>(t, ln1w + d * DIM, ln1b + d * DIM, tn_b);
        // QKV -> bf16 (64x64: 1272 blocks, R16 proven shape)
        gemm_db_kernel<64, 64><<<dim3(12, 106), 256, 0, stream>>>(
            tn_b, wbf + W_QKV + (size_t)d * 768 * DIM, nullptr, nullptr, nullptr,
            nullptr, qkv_b, ROWS, 768, DIM, 0);
        // MFMA flash attention -> bf16
        {
            dim3 grid(BATCH * HEADS, (NTOK + 63) / 64);   // (64, 14)
            attn_mfma_kernel<<<grid, 256, 0, stream>>>(qkv_b, scale + d * HEADS, ao_b);
        }
        // out proj + bias + residual -> t (32x32, R29: 1688 blocks)
        gemm_db_kernel<32, 32><<<dim3(8, 211), 256, 0, stream>>>(
            ao_b, wbf + W_OUT + (size_t)d * DIM * DIM, bout + d * DIM, t, nullptr,
            t, nullptr, ROWS, DIM, DIM, 0);
        ln_kernel<<<ROWS / 4, 256, 0, stream>>>(t, ln2w + d * DIM, ln2b + d * DIM, tn_b);
        // FF1 + gelu -> bf16 (64x64: 1696 blocks, R16 proven shape)
        gemm_db_kernel<64, 64><<<dim3(16, 106), 256, 0, stream>>>(
            tn_b, wbf + W_FF1 + (size_t)d * 1024 * DIM, ff1b + d * 1024, nullptr,
            nullptr, nullptr, ffh, ROWS, 1024, DIM, 1);
        // FF2 + bias + residual -> t (32x32, R29: 1688 blocks); t_b only
        // needed after the last layer (R26: skip dead store for d<2)
        gemm_db_kernel<32, 32><<<dim3(8, 211), 256, 0, stream>>>(
            ffh, wbf + W_FF2 + (size_t)d * DIM * 1024, ff2b + d * DIM, t, nullptr,
            t, (d == 2) ? t_b : nullptr, ROWS, DIM, 1024, 0);
    }

    // pix projection -> pixo (fp32) (32x32, R29), then scatter to output
    gemm_db_kernel<32, 32><<<dim3(8, 211), 256, 0, stream>>>(
        t_b, wbf + W_PIX, pixb, nullptr, nullptr, pixo, nullptr, ROWS, DIM, DIM, 0);
    {
        size_t total = (size_t)BATCH * IMG * IMG;
        scatter_kernel<<<dim3((unsigned)((total + 255) / 256)), 256, 0, stream>>>(pixo, out);
    }
}

// Round 13
// 333.742 us; speedup vs baseline: 1.0087x; 1.0087x over previous
//
#include <hip/hip_runtime.h>
#include <hip/hip_bf16.h>
#include <math.h>

typedef __hip_bfloat16 bf16;
typedef short bf16x8 __attribute__((ext_vector_type(8)));
typedef float floatx4 __attribute__((ext_vector_type(4)));

#define NTOK 841          // 29*29 patches
#define BATCH 8
#define DIM 256
#define HEADS 8
#define DH 32
#define IMG 457
#define HPAD 464
#define ROWS (BATCH * NTOK)   // 6728
#define LDA 40                // padded LDS row stride (bf16 elems) -> 80B

// weight segment offsets (elements) in the packed bf16 weight buffer
#define W_SPT   0
#define W_QKV   327680
#define W_OUT   917504
#define W_FF1   1114112
#define W_FF2   1900544
#define W_PIX   2686976
#define W_TOTAL 2752512

// ---------------------------------------------------------------------------
// SESSION LEDGER (R18-R29). Wins: R21 MFMA row-sum (-10.5us), R22 fixed-shift
// softmax (-14.8us), R24 Vt rotation (-2.4us). Neutral-kept: R20 fast_gelu,
// R25 Q-hoist+maskfree, R26 dead-store skip, R28 swapped-QKT packed writes.
// Failed (reverted): R18 64x128 (+78), R19 A-direct (+49), R23 BK=64 (+182),
// R27 split-K atomics (+223), R29 32x32 tiles (+2).
// Conclusion: N=256 GEMM family is latency-bound at a STRUCTURAL floor —
// not fixable by tiles/BK/prefetch/occupancy/split-K (all tested). Attn
// residual cost is its barrier skeleton (3 consecutive micro-opt neutrals).
// This file = best-measured configuration (334.2 us).
// ---------------------------------------------------------------------------

// ---------------------------------------------------------------------------
// Fast gelu (exact-erf variant): Abramowitz-Stegun 7.1.26, |err| <= 1.5e-7
// absolute on erf — far below bf16 output quantization. (R20, neutral-proven)
// ---------------------------------------------------------------------------
__device__ __forceinline__ float fast_gelu(float v) {
    float x = v * 0.70710678118654752f;
    float ax = fabsf(x);
    float t = __builtin_amdgcn_rcpf(1.0f + 0.3275911f * ax);
    float p = t * (0.254829592f +
              t * (-0.284496736f +
              t * (1.421413741f +
              t * (-1.453152027f +
              t * 1.061405429f))));
    float e = __expf(-x * x);
    float erfa = 1.0f - p * e;            // erf(|x|)
    float erfx = copysignf(erfa, x);
    return 0.5f * v * (1.0f + erfx);
}

// ---------------------------------------------------------------------------
// Convert all weight tensors fp32 -> bf16 into one packed buffer.
// ---------------------------------------------------------------------------
__global__ __launch_bounds__(256) void wconv_kernel(
    const float* __restrict__ s_spt, const float* __restrict__ s_qkv,
    const float* __restrict__ s_out, const float* __restrict__ s_ff1,
    const float* __restrict__ s_ff2, const float* __restrict__ s_pix,
    bf16* __restrict__ dst) {
    int idx = (blockIdx.x * 256 + threadIdx.x) * 4;
    const float* src; int off;
    if      (idx < W_QKV) { src = s_spt; off = W_SPT; }
    else if (idx < W_OUT) { src = s_qkv; off = W_QKV; }
    else if (idx < W_FF1) { src = s_out; off = W_OUT; }
    else if (idx < W_FF2) { src = s_ff1; off = W_FF1; }
    else if (idx < W_PIX) { src = s_ff2; off = W_FF2; }
    else                  { src = s_pix; off = W_PIX; }
    float4 v = *(const float4*)(src + (idx - off));
    union { ushort4 u; bf16 h[4]; } pk;
    pk.h[0] = __float2bfloat16(v.x);
    pk.h[1] = __float2bfloat16(v.y);
    pk.h[2] = __float2bfloat16(v.z);
    pk.h[3] = __float2bfloat16(v.w);
    *(ushort4*)(dst + idx) = pk.u;
}

// ---------------------------------------------------------------------------
// Tokenize gather -> bf16 tok[ROWS][1280], k=(c,py,px).  (R6 proven)
// ---------------------------------------------------------------------------
__global__ __launch_bounds__(256) void tokenize_kernel(const float* __restrict__ x,
                                                       bf16* __restrict__ tok) {
    int idx = blockIdx.x * 256 + threadIdx.x;
    int gm = idx / 320;
    int k4 = (idx - gm * 320) * 4;
    int b = gm / NTOK;
    int n = gm - b * NTOK;
    int hp = n / 29, wp = n - (n / 29) * 29;
    int c = k4 >> 8;
    int py = (k4 >> 4) & 15;
    int px0 = k4 & 15;
    const int dxs[5] = {0, -8, 8, -8, 8};
    const int dys[5] = {0, -8, -8, 8, 8};
    int r = hp * 16 + py - dys[c];
    r += (r < 0) ? HPAD : 0; r -= (r >= HPAD) ? HPAD : 0;
    bool rok = (r < IMG);
    union { ushort4 u; bf16 h[4]; } pk;
#pragma unroll
    for (int i = 0; i < 4; i++) {
        int s = wp * 16 + px0 + i - dxs[c];
        s += (s < 0) ? HPAD : 0; s -= (s >= HPAD) ? HPAD : 0;
        float v = 0.0f;
        if (rok && s < IMG) v = x[((size_t)b * IMG + r) * IMG + s];
        pk.h[i] = __float2bfloat16(v);
    }
    *(ushort4*)(tok + (size_t)gm * 1280 + k4) = pk.u;
}

// ---------------------------------------------------------------------------
// Double-buffered MFMA GEMM: C = A@W^T, BK=32, 4 waves (2x2).
// Proven shapes (R14/R16): 32x64 for N=256, 64x64 for wide-N. FROZEN.
// ---------------------------------------------------------------------------
template <int BM, int BN>
__global__ __launch_bounds__(256) void gemm_db_kernel(
    const bf16* __restrict__ A, const bf16* __restrict__ W,
    const float* __restrict__ bias, const float* __restrict__ resid,
    const float* __restrict__ posemb, float* __restrict__ Cf,
    bf16* __restrict__ Cb, int M, int N, int K, int act) {
    constexpr int WM = BM / 2, WN = BN / 2;
    constexpr int TI = WM / 16, TJ = WN / 16;
    constexpr int ACHUNKS = BM * 4;            // 16B chunks per A k-tile
    constexpr int BCHUNKS = BN * 4;
    static_assert(ACHUNKS <= 256 && BCHUNKS <= 256, "one chunk per thread");
    __shared__ bf16 As[2][BM * LDA];
    __shared__ bf16 Bs[2][BN * LDA];
    const int tid = threadIdx.x;
    const int m0 = blockIdx.y * BM, n0 = blockIdx.x * BN;
    const int w = tid >> 6, lane = tid & 63;
    const int wm = (w >> 1) * WM, wn = (w & 1) * WN;
    const int li = lane & 15, quad = lane >> 4;

    floatx4 acc[TI][TJ] = {};
    float4 a0, b0, a1, b1;               // ping-pong staging sets (R26)

    const int arow = tid >> 2, ako = (tid & 3) << 3;   // staging coords
    const bool a_on = tid < ACHUNKS;
    const bool b_on = tid < BCHUNKS;

    auto load_a = [&](float4& ar, int k0) {
        if (a_on) {
            int gm = m0 + arow;
            ar = make_float4(0.f, 0.f, 0.f, 0.f);
            if (gm < M) ar = *(const float4*)(A + (size_t)gm * K + k0 + ako);
        }
    };
    auto load_b = [&](float4& br, int k0) {
        if (b_on) br = *(const float4*)(W + (size_t)(n0 + arow) * K + k0 + ako);
    };
    auto store_ab = [&](int buf, const float4& ar, const float4& br) {
        if (a_on) *(float4*)&As[buf][arow * LDA + ako] = ar;
        if (b_on) *(float4*)&Bs[buf][arow * LDA + ako] = br;
    };
    auto compute = [&](int buf) {
        bf16x8 af[TI], bfr[TJ];
#pragma unroll
        for (int t = 0; t < TI; t++)
            af[t] = *(const bf16x8*)&As[buf][(wm + t * 16 + li) * LDA + quad * 8];
#pragma unroll
        for (int t = 0; t < TJ; t++)
            bfr[t] = *(const bf16x8*)&Bs[buf][(wn + t * 16 + li) * LDA + quad * 8];
#pragma unroll
        for (int ti = 0; ti < TI; ti++)
#pragma unroll
            for (int tj = 0; tj < TJ; tj++)
                acc[ti][tj] = __builtin_amdgcn_mfma_f32_16x16x32_bf16(
                    af[ti], bfr[tj], acc[ti][tj], 0, 0, 0);
    };

    const int ktiles = K >> 5;           // 8 / 32 / 40 — always even
    // prologue: tile0 -> LDS0; set0 <- tile1; set1 <- tile2
    load_a(a0, 0); load_b(b0, 0);
    store_ab(0, a0, b0);
    if (ktiles > 1) { load_a(a0, 32); load_b(b0, 32); }
    if (ktiles > 2) { load_a(a1, 64); load_b(b1, 64); }
    __syncthreads();

    for (int kt = 0; kt < ktiles; kt += 2) {
        compute(0);                                   // tile kt
        if (kt + 1 < ktiles) store_ab(1, a0, b0);     // set0 holds tile kt+1
        if (kt + 3 < ktiles) { load_a(a0, (kt + 3) << 5); load_b(b0, (kt + 3) << 5); }
        __syncthreads();
        compute(1);                                   // tile kt+1
        if (kt + 2 < ktiles) store_ab(0, a1, b1);     // set1 holds tile kt+2
        if (kt + 4 < ktiles) { load_a(a1, (kt + 4) << 5); load_b(b1, (kt + 4) << 5); }
        __syncthreads();
    }

#pragma unroll
    for (int ti = 0; ti < TI; ti++) {
#pragma unroll
        for (int r = 0; r < 4; r++) {
            int gm = m0 + wm + ti * 16 + quad * 4 + r;
            if (gm >= M) continue;
#pragma unroll
            for (int tj = 0; tj < TJ; tj++) {
                int gn = n0 + wn + tj * 16 + li;
                float v = acc[ti][tj][r];
                if (bias) v += bias[gn];
                if (act == 1) v = fast_gelu(v);
                if (posemb) v += posemb[(size_t)(gm % NTOK) * N + gn];
                if (resid) v += resid[(size_t)gm * N + gn];
                if (Cf) Cf[(size_t)gm * N + gn] = v;
                if (Cb) Cb[(size_t)gm * N + gn] = __float2bfloat16(v);
            }
        }
    }
}

// ---------------------------------------------------------------------------
// LayerNorm over last dim (256). One wave per row, 4 rows per block.
// ---------------------------------------------------------------------------
__global__ __launch_bounds__(256) void ln_kernel(const float* __restrict__ in,
                                                 const float* __restrict__ w,
                                                 const float* __restrict__ b,
                                                 bf16* __restrict__ out) {
    const int lane = threadIdx.x & 63;
    const int wv = threadIdx.x >> 6;
    const size_t row = (size_t)blockIdx.x * 4 + wv;
    const int c = lane * 4;
    float4 x = *(const float4*)&in[row * DIM + c];
    float s = x.x + x.y + x.z + x.w;
    float s2 = x.x * x.x + x.y * x.y + x.z * x.z + x.w * x.w;
#pragma unroll
    for (int off = 1; off < 64; off <<= 1) {
        s += __shfl_xor(s, off);
        s2 += __shfl_xor(s2, off);
    }
    float mean = s * (1.0f / DIM);
    float var = s2 * (1.0f / DIM) - mean * mean;
    float rstd = rsqrtf(var + 1e-5f);
    float4 w4 = *(const float4*)&w[c];
    float4 b4 = *(const float4*)&b[c];
    union { ushort4 u; bf16 h[4]; } pk;
    pk.h[0] = __float2bfloat16((x.x - mean) * rstd * w4.x + b4.x);
    pk.h[1] = __float2bfloat16((x.y - mean) * rstd * w4.y + b4.y);
    pk.h[2] = __float2bfloat16((x.z - mean) * rstd * w4.z + b4.z);
    pk.h[3] = __float2bfloat16((x.w - mean) * rstd * w4.w + b4.w);
    *(ushort4*)&out[row * DIM + c] = pk.u;
}

// ---------------------------------------------------------------------------
// MFMA flash attention, 256 threads, 1-barrier j-loop (R10 proven structure).
// R21 (-10.5us): row-sum l via PV MFMA with all-ones B. R22 (-14.8us):
// fixed-shift softmax (M=8). R24 (-2.4us): Vt j-column rotation (bank fix).
// R25 (neutral, kept): Q-frag hoist + mask-free interior tiles.
// R28 (neutral, kept): swapped QK^T operands + packed 8B Ps writes.
// ---------------------------------------------------------------------------
#define LQ 40    // Qs/Ks row stride (bf16)
#define LP 72    // Ps/Vt row stride (bf16)
__global__ __launch_bounds__(256) void attn_mfma_kernel(
    const bf16* __restrict__ qkv, const float* __restrict__ scale,
    bf16* __restrict__ out) {
    __shared__ bf16 Qs[64 * LQ];        // [i][d]
    __shared__ bf16 Ks[2][64 * LQ];     // [j][d]
    __shared__ bf16 Vt[2][32 * LP];     // [d][j-rotated]
    __shared__ bf16 Ps[64 * LP];        // [i][j], wave-private row bands

    const int tid = threadIdx.x;
    const int bh = blockIdx.x;
    const int b = bh >> 3, h = bh & 7;
    const int it = (int)gridDim.y - 1 - (int)blockIdx.y;   // longest first
    const int i0 = it * 64;
    const float sc = scale[h];
    const float sc2 = sc * 1.44269504f;          // fold scale + log2(e)
    const float mshift = -8.0f * 1.44269504f;    // fixed shift M=8 (log2 units)
    const bf16* base = qkv + (size_t)b * NTOK * 768 + h * DH;

    const int w = tid >> 6, lane = tid & 63;
    const int li = lane & 15, quad = lane >> 4;
    const int srow = tid >> 2, sd0 = (tid & 3) * 8;   // staging coords
    const int vcol = (srow + ((tid & 3) << 4)) & 63;  // R24 rotated j-column

    {
        int gi = i0 + srow;
        bf16x8 v = {};
        if (gi < NTOK) v = *(const bf16x8*)(base + (size_t)gi * 768 + sd0);
        *(bf16x8*)&Qs[srow * LQ + sd0] = v;
    }
    bf16x8 kreg = {}, vreg = {};
    {
        int gj = srow;
        if (gj < NTOK) {
            kreg = *(const bf16x8*)(base + (size_t)gj * 768 + 256 + sd0);
            vreg = *(const bf16x8*)(base + (size_t)gj * 768 + 512 + sd0);
        }
    }
    __syncthreads();   // Q staging visible -> aq can be hoisted (R25a)
    const bf16x8 aq = *(const bf16x8*)&Qs[(w * 16 + li) * LQ + quad * 8];

    // all-ones bf16 B-fragment for the row-sum MFMA (1.0bf16 = 0x3F80)
    const bf16x8 ones8 = {(short)0x3F80, (short)0x3F80, (short)0x3F80, (short)0x3F80,
                          (short)0x3F80, (short)0x3F80, (short)0x3F80, (short)0x3F80};

    floatx4 o[2] = {};
    floatx4 o2 = {};                     // running row sums (R21)
    const bool interior_ok = (i0 + 63 < NTOK);   // it <= 12
    const int gi2 = i0 + w * 16 + li;            // R28: lane's i (fixed)
    // Ps write base for this lane: row (w*16+li), col (quad*4), +16 per tj
    bf16* const psw = &Ps[(w * 16 + li) * LP + quad * 4];

    for (int jt = 0; jt <= it; jt++) {
        const int j0 = jt * 64;
        const int cur = jt & 1;
        *(bf16x8*)&Ks[cur][srow * LQ + sd0] = kreg;
#pragma unroll
        for (int u = 0; u < 8; u++) Vt[cur][(sd0 + u) * LP + vcol] = ((bf16*)&vreg)[u];
        if (jt < it) {
            int gj = j0 + 64 + srow;
            kreg = bf16x8{};
            vreg = bf16x8{};
            if (gj < NTOK) {
                kreg = *(const bf16x8*)(base + (size_t)gj * 768 + 256 + sd0);
                vreg = *(const bf16x8*)(base + (size_t)gj * 768 + 512 + sd0);
            }
        }
        __syncthreads();   // the only barrier per iteration

        // R28: swapped operands -> sacc[tj][r] = S[j0+tj*16+quad*4+r][gi2]
        floatx4 sacc[4];
#pragma unroll
        for (int tj = 0; tj < 4; tj++) {
            bf16x8 bk = *(const bf16x8*)&Ks[cur][(tj * 16 + li) * LQ + quad * 8];
            floatx4 z = {};
            sacc[tj] = __builtin_amdgcn_mfma_f32_16x16x32_bf16(bk, aq, z, 0, 0, 0);
        }

        if (jt < it && interior_ok) {
            // fast path: mask provably all-true for this wave (R25b)
#pragma unroll
            for (int tj = 0; tj < 4; tj++) {
                union { short4 u; bf16 h[4]; } pk;
#pragma unroll
                for (int r = 0; r < 4; r++)
                    pk.h[r] = __float2bfloat16(exp2f(fmaf(sacc[tj][r], sc2, mshift)));
                *(short4*)(psw + tj * 16) = pk.u;
            }
        } else {
#pragma unroll
            for (int tj = 0; tj < 4; tj++) {
                union { short4 u; bf16 h[4]; } pk;
#pragma unroll
                for (int r = 0; r < 4; r++) {
                    int j = j0 + tj * 16 + quad * 4 + r;
                    bool ok = (j < gi2) && (gi2 < NTOK);
                    float arg = ok ? fmaf(sacc[tj][r], sc2, mshift) : -1e30f;
                    pk.h[r] = __float2bfloat16(exp2f(arg));
                }
                *(short4*)(psw + tj * 16) = pk.u;
            }
        }
        // no barrier: Ps rows [16w,16w+16) written and read by wave w only.

#pragma unroll
        for (int kk = 0; kk < 64; kk += 32) {
            bf16x8 ap = *(const bf16x8*)&Ps[(w * 16 + li) * LP + kk + quad * 8];
#pragma unroll
            for (int td = 0; td < 2; td++) {
                const int kr = (2 * td + (li >> 3)) & 3;             // (d>>3)&3
                const int vc0 = (kk + quad * 8 + (kr << 4)) & 63;    // rotated base
                bf16x8 bv = *(const bf16x8*)&Vt[cur][(td * 16 + li) * LP + vc0];
                o[td] = __builtin_amdgcn_mfma_f32_16x16x32_bf16(ap, bv, o[td], 0, 0, 0);
            }
            // row-sum accumulation: every output column gets sum_j P (B = ones)
            o2 = __builtin_amdgcn_mfma_f32_16x16x32_bf16(ap, ones8, o2, 0, 0, 0);
        }
    }

#pragma unroll
    for (int r = 0; r < 4; r++) {
        int gi = i0 + w * 16 + quad * 4 + r;
        if (gi >= NTOK) continue;
        float l = o2[r];
        float iv = (gi > 0 && l > 0.0f) ? 1.0f / l : 0.0f;
        bf16* op = out + ((size_t)b * NTOK + gi) * DIM + h * DH;
        op[li]      = __float2bfloat16(o[0][r] * iv);
        op[16 + li] = __float2bfloat16(o[1][r] * iv);
    }
}

// ---------------------------------------------------------------------------
// Scatter pix [B, N, 256] fp32 -> out image [B,1,457,457] fp32 (crop)
// ---------------------------------------------------------------------------
__global__ __launch_bounds__(256) void scatter_kernel(const float* __restrict__ pix,
                                                      float* __restrict__ out) {
    const size_t total = (size_t)BATCH * IMG * IMG;
    size_t idx = (size_t)blockIdx.x * 256 + threadIdx.x;
    if (idx >= total) return;
    int b = (int)(idx / ((size_t)IMG * IMG));
    int rem = (int)(idx % ((size_t)IMG * IMG));
    int r = rem / IMG, col = rem % IMG;
    int hp = r >> 4, py = r & 15;
    int wp = col >> 4, px = col & 15;
    out[idx] = pix[((size_t)b * NTOK + hp * 29 + wp) * DIM + py * 16 + px];
}

// ---------------------------------------------------------------------------
extern "C" void kernel_launch(void* const* d_in, const int* in_sizes, int n_in,
                              void* d_out, int out_size, void* d_ws, size_t ws_size,
                              hipStream_t stream) {
    const float* x     = (const float*)d_in[0];
    const float* pos   = (const float*)d_in[1];
    const float* sptw  = (const float*)d_in[2];
    const float* sptb  = (const float*)d_in[3];
    const float* ln1w  = (const float*)d_in[4];
    const float* ln1b  = (const float*)d_in[5];
    const float* scale = (const float*)d_in[6];
    const float* wqkv  = (const float*)d_in[7];
    const float* wout  = (const float*)d_in[8];
    const float* bout  = (const float*)d_in[9];
    const float* ln2w  = (const float*)d_in[10];
    const float* ln2b  = (const float*)d_in[11];
    const float* ff1w  = (const float*)d_in[12];
    const float* ff1b  = (const float*)d_in[13];
    const float* ff2w  = (const float*)d_in[14];
    const float* ff2b  = (const float*)d_in[15];
    const float* pixw  = (const float*)d_in[16];
    const float* pixb  = (const float*)d_in[17];
    float* out = (float*)d_out;

    const size_t NT = (size_t)ROWS * DIM;
    char* ws = (char*)d_ws;
    float* t    = (float*)ws;                         ws += NT * 4;
    bf16*  tn_b = (bf16*)ws;                          ws += NT * 2;
    bf16*  t_b  = (bf16*)ws;                          ws += NT * 2;
    bf16*  ao_b = (bf16*)ws;                          ws += NT * 2;
    bf16*  wbf  = (bf16*)ws;                          ws += (size_t)W_TOTAL * 2;
    char*  big  = ws;                                  // time-shared region
    bf16*  tok   = (bf16*)big;
    bf16*  qkv_b = (bf16*)big;
    bf16*  ffh   = (bf16*)big;
    float* pixo  = (float*)big;

    wconv_kernel<<<W_TOTAL / 4 / 256, 256, 0, stream>>>(sptw, wqkv, wout, ff1w,
                                                        ff2w, pixw, wbf);
    tokenize_kernel<<<(ROWS * 320) / 256, 256, 0, stream>>>(x, tok);
    // SPT projection + bias + pos_emb -> t (fp32). 32x64 tiles: 844 blocks.
    gemm_db_kernel<32, 64><<<dim3(4, 211), 256, 0, stream>>>(
        tok, wbf + W_SPT, sptb, nullptr, pos, t, nullptr, ROWS, DIM, 1280, 0);

    for (int d = 0; d < 3; d++) {
        ln_kernel<<<ROWS / 4, 256, 0, stream>>>(t, ln1w + d * DIM, ln1b + d * DIM, tn_b);
        // QKV -> bf16 (64x64: 1272 blocks, R16 proven shape)
        gemm_db_kernel<64, 64><<<dim3(12, 106), 256, 0, stream>>>(
            tn_b, wbf + W_QKV + (size_t)d * 768 * DIM, nullptr, nullptr, nullptr,
            nullptr, qkv_b, ROWS, 768, DIM, 0);
        // MFMA flash attention -> bf16
        {
            dim3 grid(BATCH * HEADS, (NTOK + 63) / 64);   // (64, 14)
            attn_mfma_kernel<<<grid, 256, 0, stream>>>(qkv_b, scale + d * HEADS, ao_b);
        }
        // out proj + bias + residual -> t (32x64: 844 blocks)
        gemm_db_kernel<32, 64><<<dim3(4, 211), 256, 0, stream>>>(
            ao_b, wbf + W_OUT + (size_t)d * DIM * DIM, bout + d * DIM, t, nullptr,
            t, nullptr, ROWS, DIM, DIM, 0);
        ln_kernel<<<ROWS / 4, 256, 0, stream>>>(t, ln2w + d * DIM, ln2b + d * DIM, tn_b);
        // FF1 + gelu -> bf16 (64x64: 1696 blocks, R16 proven shape)
        gemm_db_kernel<64, 64><<<dim3(16, 106), 256, 0, stream>>>(
            tn_b, wbf + W_FF1 + (size_t)d * 1024 * DIM, ff1b + d * 1024, nullptr,
            nullptr, nullptr, ffh, ROWS, 1024, DIM, 1);
        // FF2 + bias + residual -> t (fp32; t_b only needed after the last
        // layer — R26: skip the dead bf16 store for d<2)
        gemm_db_kernel<32, 64><<<dim3(4, 211), 256, 0, stream>>>(
            ffh, wbf + W_FF2 + (size_t)d * DIM * 1024, ff2b + d * DIM, t, nullptr,
            t, (d == 2) ? t_b : nullptr, ROWS, DIM, 1024, 0);
    }

    // pix projection -> pixo (fp32), then scatter to output image
    gemm_db_kernel<32, 64><<<dim3(4, 211), 256, 0, stream>>>(
        t_b, wbf + W_PIX, pixb, nullptr, nullptr, pixo, nullptr, ROWS, DIM, DIM, 0);
    {
        size_t total = (size_t)BATCH * IMG * IMG;
        scatter_kernel<<<dim3((unsigned)((total + 255) / 256)), 256, 0, stream>>>(pixo, out);
    }
}